// Round 2
// baseline (339.684 us; speedup 1.0000x reference)
//
#include <hip/hip_runtime.h>
#include <hip/hip_bf16.h>

// Problem constants (B=4, S=4096, D=1024)
#define BB 4
#define SS 4096
#define DD 1024
#define MM (BB * SS)   // 16384 rows
#define KK DD          // 1024  reduction dim
#define NN (4 * DD)    // 4096  cols: [q | k | v | gate]

typedef __attribute__((ext_vector_type(8))) short bf16x8;
typedef __attribute__((ext_vector_type(4))) float f32x4;

__device__ __forceinline__ unsigned short f2bf(float f) {
  unsigned u = __float_as_uint(f);
  u += 0x7FFF + ((u >> 16) & 1);   // RNE
  return (unsigned short)(u >> 16);
}
__device__ __forceinline__ float bf2f(unsigned short h) {
  return __uint_as_float(((unsigned)h) << 16);
}

// ---------------------------------------------------------------- convert f32 -> bf16
__global__ __launch_bounds__(256) void k_convert(const float* __restrict__ src,
                                                 unsigned short* __restrict__ dst, int n4) {
  int i = blockIdx.x * blockDim.x + threadIdx.x;
  int stride = gridDim.x * blockDim.x;
  for (; i < n4; i += stride) {
    float4 v = reinterpret_cast<const float4*>(src)[i];
    ushort4 o;
    o.x = f2bf(v.x); o.y = f2bf(v.y); o.z = f2bf(v.z); o.w = f2bf(v.w);
    reinterpret_cast<ushort4*>(dst)[i] = o;
  }
}

// ---------------------------------------------------------------- GEMM (m97 structure)
// C[m][n] = sum_k A[m][k] * W[n][k]   (A: x bf16 [MM][KK], W: concat weights bf16 [NN][KK])
// 128x128 tile, BK=64, 4 waves (2x2), 16x16x32 MFMA, global_load_lds width 16.
#define BM 128
#define BN 128
#define BKSTEP 64

__global__ __launch_bounds__(256, 2) void k_gemm(const unsigned short* __restrict__ A,
                                                 const unsigned short* __restrict__ Bw,
                                                 unsigned short* __restrict__ C,
                                                 const float* __restrict__ bqkv,
                                                 const float* __restrict__ bgate) {
  __shared__ unsigned short As[BM * BKSTEP];
  __shared__ unsigned short Bs[BN * BKSTEP];

  const int bid = blockIdx.x;
  const int tn = bid & 31;        // NN/BN = 32 tiles
  const int tm = bid >> 5;        // MM/BM = 128 tiles
  const int m0 = tm * BM, n0 = tn * BN;

  const int tid = threadIdx.x;
  const int wave = tid >> 6;
  const int lane = tid & 63;
  const int wm = wave >> 1, wn = wave & 1;   // 2x2 wave grid, each wave 64x64 out

  const int r = lane & 15;
  const int kgrp = (lane >> 4) * 8;

  f32x4 acc[4][4] = {};

  for (int k0 = 0; k0 < KK; k0 += BKSTEP) {
    // Stage 16KB A-tile + 16KB B-tile. Each wave stages 4KB of each (rows wave*32..+32).
    // LDS dest is wave-uniform base + lane*16 (HW rule); linear layout matches global rows.
#pragma unroll
    for (int inst = 0; inst < 4; ++inst) {
      int o = wave * 4096 + inst * 1024 + lane * 16;  // byte offset within tile
      int row = o >> 7;                                // /128 bytes per row (64 bf16)
      int cb = o & 127;
      const char* ga = (const char*)A + ((size_t)(m0 + row) * KK + k0) * 2 + cb;
      const char* gb = (const char*)Bw + ((size_t)(n0 + row) * KK + k0) * 2 + cb;
      __builtin_amdgcn_global_load_lds(
          (const __attribute__((address_space(1))) void*)ga,
          (__attribute__((address_space(3))) void*)((char*)As + wave * 4096 + inst * 1024),
          16, 0, 0);
      __builtin_amdgcn_global_load_lds(
          (const __attribute__((address_space(1))) void*)gb,
          (__attribute__((address_space(3))) void*)((char*)Bs + wave * 4096 + inst * 1024),
          16, 0, 0);
    }
    __syncthreads();  // drains vmcnt(0) before barrier -> LDS tiles ready

#pragma unroll
    for (int kk = 0; kk < BKSTEP; kk += 32) {
      bf16x8 af[4], bfr[4];
#pragma unroll
      for (int i = 0; i < 4; ++i)
        af[i] = *reinterpret_cast<const bf16x8*>(&As[(wm * 64 + i * 16 + r) * BKSTEP + kk + kgrp]);
#pragma unroll
      for (int j = 0; j < 4; ++j)
        bfr[j] = *reinterpret_cast<const bf16x8*>(&Bs[(wn * 64 + j * 16 + r) * BKSTEP + kk + kgrp]);
#pragma unroll
      for (int i = 0; i < 4; ++i)
#pragma unroll
        for (int j = 0; j < 4; ++j)
          acc[i][j] = __builtin_amdgcn_mfma_f32_16x16x32_bf16(af[i], bfr[j], acc[i][j], 0, 0, 0);
    }
    __syncthreads();  // all reads done before next stage overwrites
  }

  // Epilogue: C/D layout col=lane&15, row=(lane>>4)*4+reg (m89/m91-verified). Add bias.
#pragma unroll
  for (int j = 0; j < 4; ++j) {
    int col = n0 + wn * 64 + j * 16 + r;
    float bias = (col < 3 * DD) ? bqkv[col] : bgate[col - 3 * DD];
#pragma unroll
    for (int i = 0; i < 4; ++i) {
      int row0 = m0 + wm * 64 + i * 16 + ((lane >> 4) << 2);
      f32x4 v = acc[i][j];
#pragma unroll
      for (int q = 0; q < 4; ++q)
        C[(size_t)(row0 + q) * NN + col] = f2bf(v[q] + bias);
    }
  }
}

// ---------------------------------------------------------------- chunked scan over S
#define NCH 128
#define CSZ (SS / NCH)  // 32

// pass1: per-chunk partial sums of k*v per (b,d)
__global__ __launch_bounds__(256) void k_pass1(const unsigned short* __restrict__ C,
                                               float* __restrict__ part) {
  int b = blockIdx.x >> 7;      // / NCH
  int c = blockIdx.x & (NCH - 1);
  int d = threadIdx.x * 4;
  float a0 = 0.f, a1 = 0.f, a2 = 0.f, a3 = 0.f;
  for (int s = c * CSZ; s < (c + 1) * CSZ; ++s) {
    size_t rowb = (size_t)(b * SS + s) * NN;
    ushort4 k4 = *(const ushort4*)&C[rowb + DD + d];
    ushort4 v4 = *(const ushort4*)&C[rowb + 2 * DD + d];
    a0 += bf2f(k4.x) * bf2f(v4.x);
    a1 += bf2f(k4.y) * bf2f(v4.y);
    a2 += bf2f(k4.z) * bf2f(v4.z);
    a3 += bf2f(k4.w) * bf2f(v4.w);
  }
  float4 o = {a0, a1, a2, a3};
  *(float4*)&part[(size_t)(b * NCH + c) * DD + d] = o;
}

// pass2: exclusive scan over the NCH chunk-partials, in place (per (b,d))
__global__ __launch_bounds__(256) void k_pass2(float* __restrict__ part) {
  int g = blockIdx.x * blockDim.x + threadIdx.x;  // [0, BB*DD)
  int b = g >> 10;
  int d = g & (DD - 1);
  float run = 0.f;
  for (int c = 0; c < NCH; ++c) {
    size_t idx = (size_t)(b * NCH + c) * DD + d;
    float t = part[idx];
    part[idx] = run;
    run += t;
  }
}

// pass3: local cumsum + chunk prefix, out = q * kv_state * sigmoid(g)
__global__ __launch_bounds__(256) void k_pass3(const unsigned short* __restrict__ C,
                                               const float* __restrict__ part,
                                               float* __restrict__ out) {
  int b = blockIdx.x >> 7;
  int c = blockIdx.x & (NCH - 1);
  int d = threadIdx.x * 4;
  float4 a = *(const float4*)&part[(size_t)(b * NCH + c) * DD + d];
  for (int s = c * CSZ; s < (c + 1) * CSZ; ++s) {
    size_t rowb = (size_t)(b * SS + s) * NN;
    ushort4 q4 = *(const ushort4*)&C[rowb + d];
    ushort4 k4 = *(const ushort4*)&C[rowb + DD + d];
    ushort4 v4 = *(const ushort4*)&C[rowb + 2 * DD + d];
    ushort4 g4 = *(const ushort4*)&C[rowb + 3 * DD + d];
    a.x += bf2f(k4.x) * bf2f(v4.x);
    a.y += bf2f(k4.y) * bf2f(v4.y);
    a.z += bf2f(k4.z) * bf2f(v4.z);
    a.w += bf2f(k4.w) * bf2f(v4.w);
    float4 o;
    o.x = bf2f(q4.x) * a.x / (1.f + __expf(-bf2f(g4.x)));
    o.y = bf2f(q4.y) * a.y / (1.f + __expf(-bf2f(g4.y)));
    o.z = bf2f(q4.z) * a.z / (1.f + __expf(-bf2f(g4.z)));
    o.w = bf2f(q4.w) * a.w / (1.f + __expf(-bf2f(g4.w)));
    *(float4*)&out[(size_t)(b * SS + s) * DD + d] = o;
  }
}

// ---------------------------------------------------------------- launch
extern "C" void kernel_launch(void* const* d_in, const int* in_sizes, int n_in,
                              void* d_out, int out_size, void* d_ws, size_t ws_size,
                              hipStream_t stream) {
  const float* x = (const float*)d_in[0];      // [B,S,D]
  const float* Wqkv = (const float*)d_in[1];   // [3D,D]
  const float* bqkv = (const float*)d_in[2];   // [3D]
  const float* Wgate = (const float*)d_in[3];  // [D,D]
  const float* bgate = (const float*)d_in[4];  // [D]
  float* out = (float*)d_out;

  char* ws = (char*)d_ws;
  unsigned short* xb = (unsigned short*)ws;                          // 32 MB  bf16 x
  unsigned short* wb = (unsigned short*)(ws + (size_t)33554432);     // 8 MB   bf16 [Wqkv;Wgate]
  unsigned short* Cc = (unsigned short*)(ws + (size_t)41943040);     // 128 MB bf16 [MM][NN]
  float* part = (float*)(ws + (size_t)176160768);                    // 2 MB   chunk partials

  // f32 -> bf16 conversions
  k_convert<<<2048, 256, 0, stream>>>(x, xb, MM * KK / 4);
  k_convert<<<1024, 256, 0, stream>>>(Wqkv, wb, 3 * DD * DD / 4);
  k_convert<<<256, 256, 0, stream>>>(Wgate, wb + 3 * DD * DD, DD * DD / 4);

  // fused qkv+gate GEMM -> C bf16 [16384][4096]
  k_gemm<<<(MM / BM) * (NN / BN), 256, 0, stream>>>(xb, wb, Cc, bqkv, bgate);

  // chunked scan of k*v along S, then final elementwise
  k_pass1<<<BB * NCH, 256, 0, stream>>>(Cc, part);
  k_pass2<<<16, 256, 0, stream>>>(part);
  k_pass3<<<BB * NCH, 256, 0, stream>>>(Cc, part, out);
}

// Round 3
// 326.587 us; speedup vs baseline: 1.0401x; 1.0401x over previous
//
#include <hip/hip_runtime.h>
#include <hip/hip_bf16.h>

// Problem constants (B=4, S=4096, D=1024)
#define BB 4
#define SS 4096
#define DD 1024
#define MM (BB * SS)   // 16384 rows
#define KK DD          // 1024  reduction dim
#define NN (4 * DD)    // 4096  cols (permuted): [q | kv-interleaved | gate]

typedef __attribute__((ext_vector_type(8))) short bf16x8;
typedef __attribute__((ext_vector_type(4))) float f32x4;

__device__ __forceinline__ unsigned short f2bf(float f) {
  unsigned u = __float_as_uint(f);
  u += 0x7FFF + ((u >> 16) & 1);   // RNE
  return (unsigned short)(u >> 16);
}
__device__ __forceinline__ float bf2f(unsigned short h) {
  return __uint_as_float(((unsigned)h) << 16);
}

// ---------------------------------------------------------------- convert f32 -> bf16
__global__ __launch_bounds__(256) void k_convert(const float* __restrict__ src,
                                                 unsigned short* __restrict__ dst, int n4) {
  int i = blockIdx.x * blockDim.x + threadIdx.x;
  int stride = gridDim.x * blockDim.x;
  for (; i < n4; i += stride) {
    float4 v = reinterpret_cast<const float4*>(src)[i];
    ushort4 o;
    o.x = f2bf(v.x); o.y = f2bf(v.y); o.z = f2bf(v.z); o.w = f2bf(v.w);
    reinterpret_cast<ushort4*>(dst)[i] = o;
  }
}

// Weight permutation: output row n' of Wb:
//   [0,1024): q rows (Wqkv row n')
//   [1024,3072): 16-col-granular k/v interleave: block t=(n'-1024)/16;
//                t even -> k row 1024+(t/2)*16+(n'&15); t odd -> v row 2048+(t/2)*16+(n'&15)
//   [3072,4096): gate rows
__global__ __launch_bounds__(256) void k_convert_wperm(const float* __restrict__ Wqkv,
                                                       const float* __restrict__ Wgate,
                                                       unsigned short* __restrict__ dst) {
  int n = blockIdx.x;
  const float* src;
  if (n < 1024) {
    src = Wqkv + (size_t)n * 1024;
  } else if (n < 3072) {
    int t = (n - 1024) >> 4;
    int d = ((t >> 1) << 4) + (n & 15);
    src = Wqkv + (size_t)(1024 + ((t & 1) << 10) + d) * 1024;
  } else {
    src = Wgate + (size_t)(n - 3072) * 1024;
  }
  unsigned short* o = dst + (size_t)n * 1024;
  int i = threadIdx.x * 4;
  float4 v = *(const float4*)(src + i);
  ushort4 u;
  u.x = f2bf(v.x); u.y = f2bf(v.y); u.z = f2bf(v.z); u.w = f2bf(v.w);
  *(ushort4*)(o + i) = u;
}

// ---------------------------------------------------------------- 256x256 phase-pipelined GEMM
// BM=BN=256, BK=32, 8 waves (2M x 4N), per-wave out 128x64 (8x4 16x16 frags).
// LDS 64KB: A[2dbuf][2half][128][32]bf16 (32KB) + B same (32KB).
// 4 phases per iteration (2 K-tiles); counted vmcnt(2) per K-tile; raw s_barrier.
#define BAR() do { asm volatile("" ::: "memory"); __builtin_amdgcn_s_barrier(); asm volatile("" ::: "memory"); } while (0)
#define VMW2() asm volatile("s_waitcnt vmcnt(2)" ::: "memory")
#define VMW0() asm volatile("s_waitcnt vmcnt(0)" ::: "memory")

__global__ __launch_bounds__(512, 2) void k_gemm2(const unsigned short* __restrict__ A,
                                                  const unsigned short* __restrict__ W,
                                                  unsigned short* __restrict__ Qd,
                                                  unsigned short* __restrict__ KVd,
                                                  unsigned short* __restrict__ Gd,
                                                  const float* __restrict__ bqkv,
                                                  const float* __restrict__ bgate) {
  __shared__ unsigned short sm[32768];  // 64 KiB

  int bid0 = blockIdx.x;
  int bid = (bid0 & 7) * 128 + (bid0 >> 3);   // XCD swizzle (nwg=1024, %8==0 -> bijective)
  int tn = bid & 15, tm = bid >> 4;           // 16 n-tiles, 64 m-tiles
  int m0 = tm * 256, n0 = tn * 256;

  int tid = threadIdx.x, wave = tid >> 6, lane = tid & 63;
  int wm = wave >> 2, wn = wave & 3;          // 2M x 4N wave grid
  int r = lane & 15, g = lane >> 4;

  // staging source (per-thread): row = base + tid/4 (+h*128), col = (tid&3)*8 ushorts, +t*32 per K-tile
  const unsigned short* Ag = A + (size_t)(m0 + (tid >> 2)) * KK + (tid & 3) * 8;
  const unsigned short* Wg = W + (size_t)(n0 + (tid >> 2)) * KK + (tid & 3) * 8;

  // LDS ushort-index layout: A: d*8192 + h*4096 + row*32 + col ; B: +16384
  int aoff = wm * 4096 + r * 32 + g * 8;                        // + d*8192 + m*512
  int boff = 16384 + (wn >> 1) * 4096 + ((wn & 1) * 64 + r) * 32 + g * 8;  // + d*8192 + n*512

#define STAGE_A(t, h, d)                                                              \
  __builtin_amdgcn_global_load_lds(                                                   \
      (const __attribute__((address_space(1))) void*)(Ag + (size_t)(h)*131072 + (t)*32), \
      (__attribute__((address_space(3))) void*)(&sm[(d)*8192 + (h)*4096 + wave * 512]), \
      16, 0, 0)
#define STAGE_B(t, h, d)                                                              \
  __builtin_amdgcn_global_load_lds(                                                   \
      (const __attribute__((address_space(1))) void*)(Wg + (size_t)(h)*131072 + (t)*32), \
      (__attribute__((address_space(3))) void*)(&sm[16384 + (d)*8192 + (h)*4096 + wave * 512]), \
      16, 0, 0)
#define LDA(m, d) (*reinterpret_cast<const bf16x8*>(&sm[aoff + (d)*8192 + (m)*512]))
#define LDB(n, d) (*reinterpret_cast<const bf16x8*>(&sm[boff + (d)*8192 + (n)*512]))
#define MFMA(x, y, c) c = __builtin_amdgcn_mfma_f32_16x16x32_bf16(x, y, c, 0, 0, 0)

  // prologue: T0 (both ops) + A-T1; wait T0, leave A-T1 in flight
  STAGE_A(0, 0, 0); STAGE_A(0, 1, 0);
  STAGE_B(0, 0, 0); STAGE_B(0, 1, 0);
  STAGE_A(1, 0, 1); STAGE_A(1, 1, 1);
  VMW2();
  BAR();

  f32x4 acc[8][4] = {};
  bf16x8 a[8], bb0, bb1;

  for (int i = 0; i < 15; ++i) {
    int t0 = 2 * i;
    // ---- ph1: Ta (dbuf0), n-frags 0,1 ; stage B-Tb
#pragma unroll
    for (int m = 0; m < 8; ++m) a[m] = LDA(m, 0);
    bb0 = LDB(0, 0); bb1 = LDB(1, 0);
    STAGE_B(t0 + 1, 0, 1); STAGE_B(t0 + 1, 1, 1);
    BAR();
    __builtin_amdgcn_s_setprio(1);
#pragma unroll
    for (int m = 0; m < 8; ++m) { MFMA(a[m], bb0, acc[m][0]); MFMA(a[m], bb1, acc[m][1]); }
    __builtin_amdgcn_s_setprio(0);
    BAR();
    // ---- ph2: Ta, n-frags 2,3 ; stage A-Tc ; vmcnt(2) (A-Tb,B-Tb retired)
    bb0 = LDB(2, 0); bb1 = LDB(3, 0);
    STAGE_A(t0 + 2, 0, 0); STAGE_A(t0 + 2, 1, 0);
    BAR();
    __builtin_amdgcn_s_setprio(1);
#pragma unroll
    for (int m = 0; m < 8; ++m) { MFMA(a[m], bb0, acc[m][2]); MFMA(a[m], bb1, acc[m][3]); }
    __builtin_amdgcn_s_setprio(0);
    VMW2();
    BAR();
    // ---- ph3: Tb (dbuf1), n-frags 0,1 ; stage B-Tc
#pragma unroll
    for (int m = 0; m < 8; ++m) a[m] = LDA(m, 1);
    bb0 = LDB(0, 1); bb1 = LDB(1, 1);
    STAGE_B(t0 + 2, 0, 0); STAGE_B(t0 + 2, 1, 0);
    BAR();
    __builtin_amdgcn_s_setprio(1);
#pragma unroll
    for (int m = 0; m < 8; ++m) { MFMA(a[m], bb0, acc[m][0]); MFMA(a[m], bb1, acc[m][1]); }
    __builtin_amdgcn_s_setprio(0);
    BAR();
    // ---- ph4: Tb, n-frags 2,3 ; stage A-Td ; vmcnt(2) (A-Tc,B-Tc retired)
    bb0 = LDB(2, 1); bb1 = LDB(3, 1);
    STAGE_A(t0 + 3, 0, 1); STAGE_A(t0 + 3, 1, 1);
    BAR();
    __builtin_amdgcn_s_setprio(1);
#pragma unroll
    for (int m = 0; m < 8; ++m) { MFMA(a[m], bb0, acc[m][2]); MFMA(a[m], bb1, acc[m][3]); }
    __builtin_amdgcn_s_setprio(0);
    VMW2();
    BAR();
  }

  // ---- peeled last iteration (Ta=30, Tb=31): only B-T31 stage remains
#pragma unroll
  for (int m = 0; m < 8; ++m) a[m] = LDA(m, 0);
  bb0 = LDB(0, 0); bb1 = LDB(1, 0);
  STAGE_B(31, 0, 1); STAGE_B(31, 1, 1);
  BAR();
#pragma unroll
  for (int m = 0; m < 8; ++m) { MFMA(a[m], bb0, acc[m][0]); MFMA(a[m], bb1, acc[m][1]); }
  BAR();
  bb0 = LDB(2, 0); bb1 = LDB(3, 0);
  BAR();
#pragma unroll
  for (int m = 0; m < 8; ++m) { MFMA(a[m], bb0, acc[m][2]); MFMA(a[m], bb1, acc[m][3]); }
  VMW0();
  BAR();
#pragma unroll
  for (int m = 0; m < 8; ++m) a[m] = LDA(m, 1);
  bb0 = LDB(0, 1); bb1 = LDB(1, 1);
  BAR();
#pragma unroll
  for (int m = 0; m < 8; ++m) { MFMA(a[m], bb0, acc[m][0]); MFMA(a[m], bb1, acc[m][1]); }
  BAR();
  bb0 = LDB(2, 1); bb1 = LDB(3, 1);
  BAR();
#pragma unroll
  for (int m = 0; m < 8; ++m) { MFMA(a[m], bb0, acc[m][2]); MFMA(a[m], bb1, acc[m][3]); }

  // ---- epilogue: C/D frag layout col=lane&15, row=(lane>>4)*4+q (m89/m91-verified)
  int growb = m0 + wm * 128 + g * 4;  // + m*16 + q
  if (tn < 4) {
    // q region
#pragma unroll
    for (int n = 0; n < 4; ++n) {
      int col = n0 + wn * 64 + n * 16 + r;
      float bias = bqkv[col];
#pragma unroll
      for (int m = 0; m < 8; ++m)
#pragma unroll
        for (int q = 0; q < 4; ++q)
          Qd[(size_t)(growb + m * 16 + q) * DD + col] = f2bf(acc[m][n][q] + bias);
    }
  } else if (tn < 12) {
    // kv region: frag pairs (2np, 2np+1) = (k, v) for d = cb/2 + np*16 + r
    int cb = n0 - 1024 + wn * 64;  // multiple of 32
#pragma unroll
    for (int np = 0; np < 2; ++np) {
      int d = (cb >> 1) + np * 16 + r;
      float bk = bqkv[1024 + d], bv = bqkv[2048 + d];
#pragma unroll
      for (int m = 0; m < 8; ++m)
#pragma unroll
        for (int q = 0; q < 4; ++q) {
          float kvv = (acc[m][2 * np][q] + bk) * (acc[m][2 * np + 1][q] + bv);
          KVd[(size_t)(growb + m * 16 + q) * DD + d] = f2bf(kvv);
        }
    }
  } else {
    // gate region: write sigmoid
    int cb0 = n0 - 3072;
#pragma unroll
    for (int n = 0; n < 4; ++n) {
      int c = cb0 + wn * 64 + n * 16 + r;
      float bias = bgate[c];
#pragma unroll
      for (int m = 0; m < 8; ++m)
#pragma unroll
        for (int q = 0; q < 4; ++q) {
          float gv = acc[m][n][q] + bias;
          Gd[(size_t)(growb + m * 16 + q) * DD + c] = f2bf(1.f / (1.f + __expf(-gv)));
        }
    }
  }
#undef STAGE_A
#undef STAGE_B
#undef LDA
#undef LDB
#undef MFMA
}

// ---------------------------------------------------------------- chunked scan over S
#define NCH 128
#define CSZ (SS / NCH)  // 32

// pass1: per-chunk partial sums of kv per (b,d)
__global__ __launch_bounds__(256) void k_pass1(const unsigned short* __restrict__ KV,
                                               float* __restrict__ part) {
  int b = blockIdx.x >> 7;
  int c = blockIdx.x & (NCH - 1);
  int d = threadIdx.x * 4;
  float a0 = 0.f, a1 = 0.f, a2 = 0.f, a3 = 0.f;
  for (int s = c * CSZ; s < (c + 1) * CSZ; ++s) {
    ushort4 kv = *(const ushort4*)&KV[(size_t)(b * SS + s) * DD + d];
    a0 += bf2f(kv.x); a1 += bf2f(kv.y); a2 += bf2f(kv.z); a3 += bf2f(kv.w);
  }
  float4 o = {a0, a1, a2, a3};
  *(float4*)&part[(size_t)(b * NCH + c) * DD + d] = o;
}

// pass2: exclusive scan over the NCH chunk-partials, in place (per (b,d))
__global__ __launch_bounds__(256) void k_pass2(float* __restrict__ part) {
  int gg = blockIdx.x * blockDim.x + threadIdx.x;  // [0, BB*DD)
  int b = gg >> 10;
  int d = gg & (DD - 1);
  float run = 0.f;
  for (int c = 0; c < NCH; ++c) {
    size_t idx = (size_t)(b * NCH + c) * DD + d;
    float t = part[idx];
    part[idx] = run;
    run += t;
  }
}

// pass3: local cumsum + chunk prefix; out = q * kv_state * g (g pre-sigmoided)
__global__ __launch_bounds__(256) void k_pass3(const unsigned short* __restrict__ Q,
                                               const unsigned short* __restrict__ KV,
                                               const unsigned short* __restrict__ G,
                                               const float* __restrict__ part,
                                               float* __restrict__ out) {
  int b = blockIdx.x >> 7;
  int c = blockIdx.x & (NCH - 1);
  int d = threadIdx.x * 4;
  float4 a = *(const float4*)&part[(size_t)(b * NCH + c) * DD + d];
  for (int s = c * CSZ; s < (c + 1) * CSZ; ++s) {
    size_t rowb = (size_t)(b * SS + s) * DD;
    ushort4 q4 = *(const ushort4*)&Q[rowb + d];
    ushort4 kv4 = *(const ushort4*)&KV[rowb + d];
    ushort4 g4 = *(const ushort4*)&G[rowb + d];
    a.x += bf2f(kv4.x); a.y += bf2f(kv4.y); a.z += bf2f(kv4.z); a.w += bf2f(kv4.w);
    float4 o;
    o.x = bf2f(q4.x) * a.x * bf2f(g4.x);
    o.y = bf2f(q4.y) * a.y * bf2f(g4.y);
    o.z = bf2f(q4.z) * a.z * bf2f(g4.z);
    o.w = bf2f(q4.w) * a.w * bf2f(g4.w);
    *(float4*)&out[rowb + d] = o;
  }
}

// ---------------------------------------------------------------- launch
extern "C" void kernel_launch(void* const* d_in, const int* in_sizes, int n_in,
                              void* d_out, int out_size, void* d_ws, size_t ws_size,
                              hipStream_t stream) {
  const float* x = (const float*)d_in[0];      // [B,S,D]
  const float* Wqkv = (const float*)d_in[1];   // [3D,D]
  const float* bqkv = (const float*)d_in[2];   // [3D]
  const float* Wgate = (const float*)d_in[3];  // [D,D]
  const float* bgate = (const float*)d_in[4];  // [D]
  float* out = (float*)d_out;

  char* ws = (char*)d_ws;
  unsigned short* xb = (unsigned short*)ws;                        // 32 MB bf16 x
  unsigned short* wb = (unsigned short*)(ws + (size_t)33554432);   // 8 MB  bf16 permuted W
  unsigned short* Qd = (unsigned short*)(ws + (size_t)41943040);   // 32 MB
  unsigned short* KVd = (unsigned short*)(ws + (size_t)75497472);  // 32 MB
  unsigned short* Gd = (unsigned short*)(ws + (size_t)109051904);  // 32 MB
  float* part = (float*)(ws + (size_t)142606336);                  // 2 MB

  k_convert<<<2048, 256, 0, stream>>>(x, xb, MM * KK / 4);
  k_convert_wperm<<<4096, 256, 0, stream>>>(Wqkv, Wgate, wb);

  k_gemm2<<<1024, 512, 0, stream>>>(xb, wb, Qd, KVd, Gd, bqkv, bgate);

  k_pass1<<<BB * NCH, 256, 0, stream>>>(KVd, part);
  k_pass2<<<16, 256, 0, stream>>>(part);
  k_pass3<<<BB * NCH, 256, 0, stream>>>(Qd, KVd, Gd, part, out);
}